// Round 5
// baseline (1989.255 us; speedup 1.0000x reference)
//
#include <hip/hip_runtime.h>

#define B_ROWS 16384
#define D_IN   1024
#define NW1P   2816   // padded GEMM1 N: 10*256 expert + 3*64 gate + 64 pad
#define H2N    128

typedef unsigned short u16;
typedef __attribute__((ext_vector_type(4)))  float f32x4;
typedef __attribute__((ext_vector_type(16))) float f32x16;
typedef __attribute__((ext_vector_type(8)))  short s16x8;
typedef __attribute__((ext_vector_type(8)))  unsigned short u16x8;

__device__ __forceinline__ u16 f2bf(float f){
  unsigned int u = __float_as_uint(f);
  u += 0x7FFFu + ((u >> 16) & 1u);
  return (u16)(u >> 16);
}
__device__ __forceinline__ float bf2f(u16 h){
  return __uint_as_float(((unsigned int)h) << 16);
}

// async global->LDS, 16B per lane. LDS dest must be linear (wave base + lane*16).
__device__ __forceinline__ void gload_lds16(const void* gp, void* lp){
  typedef __attribute__((address_space(1))) unsigned int GUI;
  typedef __attribute__((address_space(3))) unsigned int LUI;
  __builtin_amdgcn_global_load_lds((GUI*)(unsigned long long)gp,
                                   (LUI*)(unsigned int)(unsigned long long)lp,
                                   16, 0, 0);
}

// ---------------- weight packing ----------------
__global__ void pack_w1_kernel(const float* __restrict__ sW1, const float* __restrict__ dW1,
                               const float* __restrict__ gW1, const float* __restrict__ sb1,
                               const float* __restrict__ db1, const float* __restrict__ gb1,
                               u16* __restrict__ W1T, float* __restrict__ b1c)
{
  __shared__ float t[64*65];
  const int tid = threadIdx.x;
  const int bid = blockIdx.x;          // 44 * 16
  const int ntile = bid >> 4, dtile = bid & 15;
  const int n0 = ntile*64, d0 = dtile*64;
  #pragma unroll
  for (int i=0;i<16;++i){
    int idx = i*256 + tid;
    int dd = idx >> 6, nn = idx & 63;
    int n = n0 + nn, d = d0 + dd;
    float v;
    if (n < 2560){
      int e = n >> 8, h = n & 255;
      v = (e < 4) ? sW1[((size_t)e*D_IN + d)*256 + h]
                  : dW1[((size_t)(e-4)*D_IN + d)*256 + h];
    } else if (n < 2752){
      int t2 = n - 2560; int gg = t2 >> 6, k = t2 & 63;
      v = gW1[((size_t)gg*D_IN + d)*64 + k];
    } else v = 0.f;
    t[nn*65 + dd] = v;
  }
  __syncthreads();
  #pragma unroll
  for (int i=0;i<16;++i){
    int idx = i*256 + tid;
    int nn = idx >> 6, dd = idx & 63;
    W1T[(size_t)(n0+nn)*D_IN + d0 + dd] = f2bf(t[nn*65 + dd]);
  }
  if (dtile == 0 && tid < 64){
    int n = n0 + tid; float v;
    if (n < 2560){ int e = n>>8, h = n&255; v = (e<4)? sb1[e*256+h] : db1[(e-4)*256+h]; }
    else if (n < 2752){ int t2 = n-2560; v = gb1[(t2>>6)*64 + (t2&63)]; }
    else v = 0.f;
    b1c[n] = v;
  }
}

__global__ void pack_w2_kernel(const float* __restrict__ sW2, const float* __restrict__ dW2,
                               const float* __restrict__ sb2, const float* __restrict__ db2,
                               u16* __restrict__ W2T, float* __restrict__ b2c)
{
  __shared__ float t[64*65];
  const int tid = threadIdx.x;
  const int bid = blockIdx.x;          // 10 * 2 * 4
  const int e = bid >> 3, ot = (bid >> 2) & 1, ht = bid & 3;
  const int o0 = ot*64, h0 = ht*64;
  #pragma unroll
  for (int i=0;i<16;++i){
    int idx = i*256 + tid;
    int hh = idx >> 6, oo = idx & 63;
    float v = (e < 4) ? sW2[((size_t)e*256 + h0+hh)*128 + o0+oo]
                      : dW2[((size_t)(e-4)*256 + h0+hh)*128 + o0+oo];
    t[oo*65 + hh] = v;
  }
  __syncthreads();
  #pragma unroll
  for (int i=0;i<16;++i){
    int idx = i*256 + tid;
    int oo = idx >> 6, hh = idx & 63;
    W2T[(size_t)e*32768 + (size_t)(o0+oo)*256 + h0 + hh] = f2bf(t[oo*65 + hh]);
  }
  if (ht == 0 && ot == 0 && tid < 128)
    b2c[e*128 + tid] = (e < 4) ? sb2[e*128 + tid] : db2[(e-4)*128 + tid];
}

__global__ void cast_x_kernel(const float* __restrict__ x, u16* __restrict__ xb)
{
  const size_t i = ((size_t)blockIdx.x*256 + threadIdx.x)*8;
  f32x4 a = *(const f32x4*)(x + i);
  f32x4 b = *(const f32x4*)(x + i + 4);
  u16x8 r;
  r[0]=f2bf(a[0]); r[1]=f2bf(a[1]); r[2]=f2bf(a[2]); r[3]=f2bf(a[3]);
  r[4]=f2bf(b[0]); r[5]=f2bf(b[1]); r[6]=f2bf(b[2]); r[7]=f2bf(b[3]);
  *(u16x8*)(xb + i) = r;
}

// ---------------- GEMM1: 256x256 tile, BK=32, 32x32x16 MFMA, 2 blocks/CU ----------------
// LDS 64 KB (2 buf x (A 16KB + B 16KB)) -> 2 blocks resident per CU: sibling-block
// wave overlap hides stage/barrier/read serialization (m114 mechanism).
// 8 waves (2m x 4n), wave tile 128x64: 16 MFMA + 12 ds_read_b128 per K-tile.
// LDS rows [256][4 slots of 8 elems]; XOR swizzle phys = chunk ^ ((row>>1)&3);
// adjacent per-lane reads alternate slot parity (avoids pipelined same-bank runs).

#define VM0 asm volatile("s_waitcnt vmcnt(0)" ::: "memory")
#define BAR __builtin_amdgcn_s_barrier()

#define STAGE32(T, BUF) do{ \
  const u16* ga_ = aStg + (T)*32; \
  const u16* gb_ = bStg + (T)*32; \
  gload_lds16(ga_,          &L[BUF][0][tid*8]); \
  gload_lds16(ga_ + 131072, &L[BUF][0][4096 + tid*8]); \
  gload_lds16(gb_,          &L[BUF][1][tid*8]); \
  gload_lds16(gb_ + 131072, &L[BUF][1][4096 + tid*8]); \
}while(0)

#define COMPUTE32(BUF) do{ \
  s16x8 av[4][2], bv[2][2]; \
  _Pragma("unroll") for (int mf=0;mf<4;++mf){ \
    av[mf][0] = *(const s16x8*)&L[BUF][0][(wm*128 + mf*32 + l31)*32 + sk0]; \
    av[mf][1] = *(const s16x8*)&L[BUF][0][(wm*128 + mf*32 + l31)*32 + sk1]; \
  } \
  _Pragma("unroll") for (int nf=0;nf<2;++nf){ \
    bv[nf][0] = *(const s16x8*)&L[BUF][1][(wn*64 + nf*32 + l31)*32 + sk0]; \
    bv[nf][1] = *(const s16x8*)&L[BUF][1][(wn*64 + nf*32 + l31)*32 + sk1]; \
  } \
  _Pragma("unroll") for (int ks=0;ks<2;++ks){ \
    _Pragma("unroll") for (int mf=0;mf<4;++mf){ \
      acc[mf][0] = __builtin_amdgcn_mfma_f32_32x32x16_bf16(av[mf][ks], bv[0][ks], acc[mf][0], 0, 0, 0); \
      acc[mf][1] = __builtin_amdgcn_mfma_f32_32x32x16_bf16(av[mf][ks], bv[1][ks], acc[mf][1], 0, 0, 0); \
    } \
  } \
}while(0)

__global__ __launch_bounds__(512, 4) void gemm1_kernel(
    const u16* __restrict__ Xb, const u16* __restrict__ W1T,
    const float* __restrict__ b1c, u16* __restrict__ Hb)
{
  __shared__ __attribute__((aligned(16))) u16 L[2][2][8192];   // 64 KiB
  const int tid  = threadIdx.x;
  const int lane = tid & 63;
  const int wid  = tid >> 6;
  const int wm   = wid >> 2;          // 0..1
  const int wn   = wid & 3;           // 0..3

  const int bid = blockIdx.x;                         // 704 = 64 mt * 11 nt
  const int swz = (bid & 7)*88 + (bid >> 3);          // bijective XCD swizzle (704%8==0)
  const int mt  = swz / 11;                           // mt-major (round-2/3 layout, FETCH ~91MB)
  const int nt  = swz - mt*11;
  const int row0 = mt*256, col0 = nt*256;

  const int l31 = lane & 31, l5 = lane >> 5;
  const int rsw = (l31 >> 1) & 3;                     // read-side row swizzle key
  const int sk0 = ((l5    ) ^ rsw) << 3;              // chunk 0|l5
  const int sk1 = ((2 | l5) ^ rsw) << 3;              // chunk 2|l5

  // staging: thread -> row (tid>>2), phys slot (tid&3); pre-swizzled source
  // chunk = (tid&3) ^ ((row>>1)&3) = (tid&3) ^ ((tid>>3)&3)
  const int sRow = tid >> 2;                          // 0..127 (+128 for 2nd gld)
  const int sSl  = (tid & 3) ^ ((tid >> 3) & 3);
  const u16* aStg = Xb  + (size_t)(row0 + sRow)*D_IN + sSl*8;
  const u16* bStg = W1T + (size_t)(col0 + sRow)*D_IN + sSl*8;

  f32x16 acc[4][2];
  #pragma unroll
  for (int mf=0;mf<4;++mf)
    #pragma unroll
    for (int nf=0;nf<2;++nf)
      #pragma unroll
      for (int r=0;r<16;++r) acc[mf][nf][r] = 0.f;

  STAGE32(0, 0);
  VM0; BAR;

  #pragma unroll 1
  for (int t=0; t<32; t+=2){
    STAGE32(t+1, 1);                    // t+1 <= 31 always
    COMPUTE32(0);
    VM0; BAR;
    if (t+2 < 32) STAGE32(t+2, 0);
    COMPUTE32(1);
    VM0; BAR;
  }

  // epilogue: bias + relu + bf16 store.  C/D: col = lane&31, row = (r&3)+8*(r>>2)+4*l5
  const float b0v = b1c[col0 + wn*64 + l31];
  const float b1v = b1c[col0 + wn*64 + 32 + l31];
  #pragma unroll
  for (int mf=0;mf<4;++mf){
    const int rbase = row0 + wm*128 + mf*32 + 4*l5;
    #pragma unroll
    for (int nf=0;nf<2;++nf){
      const int col = col0 + wn*64 + nf*32 + l31;
      const float bias = nf ? b1v : b0v;
      #pragma unroll
      for (int r=0;r<16;++r){
        const int row = rbase + (r&3) + 8*(r>>2);
        float v = acc[mf][nf][r] + bias;
        v = v > 0.f ? v : 0.f;
        Hb[(size_t)row*NW1P + col] = f2bf(v);
      }
    }
  }
}

// ---------------- gates: softmax((relu-hidden) @ gW2 + gb2) ----------------
__global__ void gates_kernel(const u16* __restrict__ Hb, const float* __restrict__ gW2,
                             const float* __restrict__ gb2, float* __restrict__ gts)
{
  __shared__ float wsm[64*6];
  __shared__ float bsm[6];
  const int tid = threadIdx.x;
  const int bid = blockIdx.x;                 // 3 * 64 blocks
  const int g = bid >> 6;
  const int b = ((bid & 63) << 8) + tid;
  if (tid < 6) bsm[tid] = gb2[g*6 + tid];
  for (int i = tid; i < 384; i += 256) wsm[i] = gW2[g*384 + i];
  __syncthreads();
  const u16* gh = Hb + (size_t)b*NW1P + 2560 + g*64;
  float lg[6];
  #pragma unroll
  for (int e=0;e<6;++e) lg[e] = bsm[e];
  #pragma unroll
  for (int k8=0;k8<8;++k8){
    u16x8 hv = *(const u16x8*)&gh[k8*8];
    #pragma unroll
    for (int j=0;j<8;++j){
      const float h = bf2f(hv[j]);
      const int k = k8*8 + j;
      #pragma unroll
      for (int e=0;e<6;++e) lg[e] += h * wsm[k*6 + e];
    }
  }
  float mx = lg[0];
  #pragma unroll
  for (int e=1;e<6;++e) mx = fmaxf(mx, lg[e]);
  float s = 0.f; float p[6];
  #pragma unroll
  for (int e=0;e<6;++e){ p[e] = expf(lg[e]-mx); s += p[e]; }
  const float inv = 1.f / s;
  float* dst = gts + ((size_t)g*B_ROWS + b)*6;
  #pragma unroll
  for (int e=0;e<6;++e) dst[e] = p[e]*inv;
}

// ------- GEMM2 fused with gate-weighted combine -------
__global__ __launch_bounds__(256, 2) void gemm2_kernel(
    const u16* __restrict__ Hb, const u16* __restrict__ W2T,
    const float* __restrict__ b2c, const float* __restrict__ gts,
    float* __restrict__ outp)
{
  __shared__ __attribute__((aligned(16))) u16 lds[2][2][128*32];
  const int tid = threadIdx.x;
  const int lane = tid & 63;
  const int wid = tid >> 6;
  const int wm = wid >> 1, wn = wid & 1;
  const int bid = blockIdx.x;                 // 128 * 3
  const int mt = bid / 3;
  const int g  = bid - mt*3;
  const int row0 = mt*128;

  const int sr = tid >> 2;
  const int sk = (tid & 3) << 3;

  const f32x4 fz = {0.f,0.f,0.f,0.f};
  f32x4 oacc[4][4], eacc[4][4];
  #pragma unroll
  for (int m=0;m<4;++m)
    #pragma unroll
    for (int n=0;n<4;++n){ oacc[m][n] = fz; eacc[m][n] = fz; }

  auto stage = [&](int s, int buf){
    const int e  = s >> 3;
    const int ks = s & 7;
    const int eidv = (e < 4) ? e : (g*2 + e);
    const u16* ga = Hb  + (size_t)(row0 + sr)*NW1P + eidv*256 + ks*32 + sk;
    const u16* gb = W2T + (size_t)eidv*32768 + (size_t)sr*256 + ks*32 + sk;
    u16* la = &lds[buf][0][tid*8];
    u16* lb = &lds[buf][1][tid*8];
    #pragma unroll
    for (int j=0;j<2;++j){
      gload_lds16(ga + (size_t)j*64*NW1P, la + j*2048);
      gload_lds16(gb + (size_t)j*64*256,  lb + j*2048);
    }
  };

  const int fr = lane & 15;
  const int ko = (lane >> 4) << 3;
  const int r4 = (lane >> 4) << 2;

  stage(0, 0);
  __syncthreads();

  for (int s=0; s<48; ++s){
    const int buf = s & 1;
    if (s+1 < 48) stage(s+1, buf^1);
    s16x8 af[4], bfv[4];
    #pragma unroll
    for (int m=0;m<4;++m)
      af[m] = *(const s16x8*)&lds[buf][0][(wm*64 + m*16 + fr)*32 + ko];
    #pragma unroll
    for (int n=0;n<4;++n)
      bfv[n] = *(const s16x8*)&lds[buf][1][(wn*64 + n*16 + fr)*32 + ko];
    #pragma unroll
    for (int m=0;m<4;++m)
      #pragma unroll
      for (int n=0;n<4;++n)
        eacc[m][n] = __builtin_amdgcn_mfma_f32_16x16x32_bf16(af[m], bfv[n], eacc[m][n], 0, 0, 0);
    if ((s & 7) == 7){
      const int e = s >> 3;
      const int eidv = (e < 4) ? e : (g*2 + e);
      #pragma unroll
      for (int m=0;m<4;++m){
        const int lr = wm*64 + m*16 + r4;
        float w[4];
        #pragma unroll
        for (int r=0;r<4;++r)
          w[r] = gts[((size_t)g*B_ROWS + row0 + lr + r)*6 + e];
        #pragma unroll
        for (int n=0;n<4;++n){
          const int c = wn*64 + n*16 + fr;
          const float bias = b2c[eidv*128 + c];
          #pragma unroll
          for (int r=0;r<4;++r){
            float v = eacc[m][n][r] + bias;
            v = v > 0.f ? v : 0.f;
            oacc[m][n][r] += w[r]*v;
          }
          eacc[m][n] = fz;
        }
      }
    }
    __syncthreads();
  }

  #pragma unroll
  for (int m=0;m<4;++m){
    const int lr = wm*64 + m*16 + r4;
    #pragma unroll
    for (int n=0;n<4;++n){
      const int c = wn*64 + n*16 + fr;
      #pragma unroll
      for (int r=0;r<4;++r)
        outp[((size_t)g*B_ROWS + row0 + lr + r)*H2N + c] = oacc[m][n][r];
    }
  }
}

extern "C" void kernel_launch(void* const* d_in, const int* in_sizes, int n_in,
                              void* d_out, int out_size, void* d_ws, size_t ws_size,
                              hipStream_t stream)
{
  (void)in_sizes; (void)n_in; (void)out_size; (void)ws_size;
  const float* x   = (const float*)d_in[0];
  const float* sW1 = (const float*)d_in[2];
  const float* sb1 = (const float*)d_in[3];
  const float* sW2 = (const float*)d_in[4];
  const float* sb2 = (const float*)d_in[5];
  const float* dW1 = (const float*)d_in[6];
  const float* db1 = (const float*)d_in[7];
  const float* dW2 = (const float*)d_in[8];
  const float* db2 = (const float*)d_in[9];
  const float* gW1 = (const float*)d_in[10];
  const float* gb1 = (const float*)d_in[11];
  const float* gW2 = (const float*)d_in[12];
  const float* gb2 = (const float*)d_in[13];
  float* outp = (float*)d_out;

  char* ws = (char*)d_ws;
  u16*   Xb  = (u16*  )(ws + 0);          // 16384*1024*2      = 33554432
  u16*   W1T = (u16*  )(ws + 33554432);   // 2816*1024*2       =  5767168
  float* b1c = (float*)(ws + 39321600);   // 2816*4            =    11264
  u16*   W2T = (u16*  )(ws + 39332864);   // 10*128*256*2      =   655360
  float* b2c = (float*)(ws + 39988224);   // 10*128*4          =     5120
  float* gts = (float*)(ws + 39993344);   // 3*16384*6*4       =  1179648
  u16*   Hb  = (u16*  )(ws + 41172992);   // 16384*2816*2      = 92274688  (end ~133.4 MB)

  pack_w1_kernel<<<dim3(704),  dim3(256), 0, stream>>>(sW1,dW1,gW1,sb1,db1,gb1,W1T,b1c);
  pack_w2_kernel<<<dim3(80),   dim3(256), 0, stream>>>(sW2,dW2,sb2,db2,W2T,b2c);
  cast_x_kernel <<<dim3(8192), dim3(256), 0, stream>>>(x, Xb);
  gemm1_kernel  <<<dim3(704),  dim3(512), 0, stream>>>(Xb, W1T, b1c, Hb);
  gates_kernel  <<<dim3(192),  dim3(256), 0, stream>>>(Hb, gW2, gb2, gts);
  gemm2_kernel  <<<dim3(384),  dim3(256), 0, stream>>>(Hb, W2T, b2c, gts, outp);
}

// Round 6
// 217.767 us; speedup vs baseline: 9.1348x; 9.1348x over previous
//
#include <hip/hip_runtime.h>

#define B_ROWS 16384
#define D_IN   1024
#define NW1P   2816   // padded GEMM1 N: 10*256 expert + 3*64 gate + 64 pad
#define H2N    128

typedef unsigned short u16;
typedef __attribute__((ext_vector_type(4)))  float f32x4;
typedef __attribute__((ext_vector_type(16))) float f32x16;
typedef __attribute__((ext_vector_type(8)))  short s16x8;
typedef __attribute__((ext_vector_type(8)))  unsigned short u16x8;

__device__ __forceinline__ u16 f2bf(float f){
  unsigned int u = __float_as_uint(f);
  u += 0x7FFFu + ((u >> 16) & 1u);
  return (u16)(u >> 16);
}
__device__ __forceinline__ float bf2f(u16 h){
  return __uint_as_float(((unsigned int)h) << 16);
}

// async global->LDS, 16B per lane. LDS dest must be linear (wave base + lane*16).
__device__ __forceinline__ void gload_lds16(const void* gp, void* lp){
  typedef __attribute__((address_space(1))) unsigned int GUI;
  typedef __attribute__((address_space(3))) unsigned int LUI;
  __builtin_amdgcn_global_load_lds((GUI*)(unsigned long long)gp,
                                   (LUI*)(unsigned int)(unsigned long long)lp,
                                   16, 0, 0);
}

// ---------------- weight packing ----------------
__global__ void pack_w1_kernel(const float* __restrict__ sW1, const float* __restrict__ dW1,
                               const float* __restrict__ gW1, const float* __restrict__ sb1,
                               const float* __restrict__ db1, const float* __restrict__ gb1,
                               u16* __restrict__ W1T, float* __restrict__ b1c)
{
  __shared__ float t[64*65];
  const int tid = threadIdx.x;
  const int bid = blockIdx.x;          // 44 * 16
  const int ntile = bid >> 4, dtile = bid & 15;
  const int n0 = ntile*64, d0 = dtile*64;
  #pragma unroll
  for (int i=0;i<16;++i){
    int idx = i*256 + tid;
    int dd = idx >> 6, nn = idx & 63;
    int n = n0 + nn, d = d0 + dd;
    float v;
    if (n < 2560){
      int e = n >> 8, h = n & 255;
      v = (e < 4) ? sW1[((size_t)e*D_IN + d)*256 + h]
                  : dW1[((size_t)(e-4)*D_IN + d)*256 + h];
    } else if (n < 2752){
      int t2 = n - 2560; int gg = t2 >> 6, k = t2 & 63;
      v = gW1[((size_t)gg*D_IN + d)*64 + k];
    } else v = 0.f;
    t[nn*65 + dd] = v;
  }
  __syncthreads();
  #pragma unroll
  for (int i=0;i<16;++i){
    int idx = i*256 + tid;
    int nn = idx >> 6, dd = idx & 63;
    W1T[(size_t)(n0+nn)*D_IN + d0 + dd] = f2bf(t[nn*65 + dd]);
  }
  if (dtile == 0 && tid < 64){
    int n = n0 + tid; float v;
    if (n < 2560){ int e = n>>8, h = n&255; v = (e<4)? sb1[e*256+h] : db1[(e-4)*256+h]; }
    else if (n < 2752){ int t2 = n-2560; v = gb1[(t2>>6)*64 + (t2&63)]; }
    else v = 0.f;
    b1c[n] = v;
  }
}

__global__ void pack_w2_kernel(const float* __restrict__ sW2, const float* __restrict__ dW2,
                               const float* __restrict__ sb2, const float* __restrict__ db2,
                               u16* __restrict__ W2T, float* __restrict__ b2c)
{
  __shared__ float t[64*65];
  const int tid = threadIdx.x;
  const int bid = blockIdx.x;          // 10 * 2 * 4
  const int e = bid >> 3, ot = (bid >> 2) & 1, ht = bid & 3;
  const int o0 = ot*64, h0 = ht*64;
  #pragma unroll
  for (int i=0;i<16;++i){
    int idx = i*256 + tid;
    int hh = idx >> 6, oo = idx & 63;
    float v = (e < 4) ? sW2[((size_t)e*256 + h0+hh)*128 + o0+oo]
                      : dW2[((size_t)(e-4)*256 + h0+hh)*128 + o0+oo];
    t[oo*65 + hh] = v;
  }
  __syncthreads();
  #pragma unroll
  for (int i=0;i<16;++i){
    int idx = i*256 + tid;
    int oo = idx >> 6, hh = idx & 63;
    W2T[(size_t)e*32768 + (size_t)(o0+oo)*256 + h0 + hh] = f2bf(t[oo*65 + hh]);
  }
  if (ht == 0 && ot == 0 && tid < 128)
    b2c[e*128 + tid] = (e < 4) ? sb2[e*128 + tid] : db2[(e-4)*128 + tid];
}

__global__ void cast_x_kernel(const float* __restrict__ x, u16* __restrict__ xb)
{
  const size_t i = ((size_t)blockIdx.x*256 + threadIdx.x)*8;
  f32x4 a = *(const f32x4*)(x + i);
  f32x4 b = *(const f32x4*)(x + i + 4);
  u16x8 r;
  r[0]=f2bf(a[0]); r[1]=f2bf(a[1]); r[2]=f2bf(a[2]); r[3]=f2bf(a[3]);
  r[4]=f2bf(b[0]); r[5]=f2bf(b[1]); r[6]=f2bf(b[2]); r[7]=f2bf(b[3]);
  *(u16x8*)(xb + i) = r;
}

// ---------------- GEMM1: 256x256 tile, BK=64, 32x32x16 MFMA ----------------
// A staged in LDS (32 KB/buf, dbuf = 64 KB total); B loaded DIRECTLY global->reg
// (L2-hot 5.7 MB weight), double-buffered bvA/bvB across tiles. LDS traffic per
// K-tile = 160 KB (< MFMA 2048 cyc at ~112 B/cyc) -> LDS no longer binding pipe.
// 8 waves (2m x 4n); per wave per K-tile: 4 gld_lds + 8 global b128 + 16 ds_read
// + 32 MFMA. One vmcnt(0)+barrier per tile (issue-to-wait gap = full tile).

#define VM0 asm volatile("s_waitcnt vmcnt(0)" ::: "memory")
#define BAR __builtin_amdgcn_s_barrier()

#define SGA(T, BUF) do{ \
  const u16* ga_ = aStg + (T)*64; \
  _Pragma("unroll") for (int j=0;j<4;++j) \
    gload_lds16(ga_ + j*65536, &L[BUF][j*4096 + tid*8]); \
}while(0)

#define LOADB(T, BV) do{ \
  const u16* pb0_ = pB0 + (T)*64; \
  const u16* pb1_ = pB1 + (T)*64; \
  _Pragma("unroll") for (int kk=0;kk<4;++kk){ \
    BV[kk][0] = *(const s16x8*)(pb0_ + kk*16); \
    BV[kk][1] = *(const s16x8*)(pb1_ + kk*16); \
  } \
}while(0)

#define COMPUTE(BUF, BV) do{ \
  _Pragma("unroll") for (int kk=0;kk<4;++kk){ \
    s16x8 av[4]; \
    _Pragma("unroll") for (int mf=0;mf<4;++mf){ \
      const int row_ = wm*128 + mf*32 + l31; \
      av[mf] = *(const s16x8*)&L[BUF][(row_<<6) + (((((kk<<1)|l5)) ^ (row_&7))<<3)]; \
    } \
    __builtin_amdgcn_s_setprio(1); \
    _Pragma("unroll") for (int mf=0;mf<4;++mf){ \
      acc[mf][0] = __builtin_amdgcn_mfma_f32_32x32x16_bf16(av[mf], BV[kk][0], acc[mf][0], 0, 0, 0); \
      acc[mf][1] = __builtin_amdgcn_mfma_f32_32x32x16_bf16(av[mf], BV[kk][1], acc[mf][1], 0, 0, 0); \
    } \
    __builtin_amdgcn_s_setprio(0); \
  } \
}while(0)

__global__ __launch_bounds__(512, 2) void gemm1_kernel(
    const u16* __restrict__ Xb, const u16* __restrict__ W1T,
    const float* __restrict__ b1c, u16* __restrict__ Hb)
{
  __shared__ __attribute__((aligned(16))) u16 L[2][16384];   // A only: 2 x 32 KB
  const int tid  = threadIdx.x;
  const int lane = tid & 63;
  const int wid  = tid >> 6;
  const int wm   = wid >> 2;          // 0..1
  const int wn   = wid & 3;           // 0..3

  // 704 blocks = 64 mt x 11 nt. Per-XCD: mt-fast (8 A panels = 4 MB L2-resident),
  // nt slow (B strip 512 KB hot for 8 consecutive blocks).
  const int bid = blockIdx.x;
  const int xcd = bid & 7, pos = bid >> 3;        // pos 0..87
  const int mt  = xcd*8 + (pos & 7);              // 0..63
  const int nt  = pos >> 3;                       // 0..10
  const int row0 = mt*256, col0 = nt*256;

  const int l31 = lane & 31, l5 = lane >> 5;

  // A staging: thread -> row (tid>>3), phys slot (tid&7); pre-swizzled source
  // slot = (tid&7) ^ ((tid>>3)&7)  [r2/r3-verified conflict-free]
  const int sRow = tid >> 3;
  const int sSl  = (tid & 7) ^ (sRow & 7);
  const u16* aStg = Xb + (size_t)(row0 + sRow)*D_IN + sSl*8;

  // B direct-from-global lane pointers (nf=0: cols +0..31, nf=1: cols +32..63)
  const u16* pB0 = W1T + (size_t)(col0 + wn*64 + l31)*D_IN + l5*8;
  const u16* pB1 = pB0 + (size_t)32*D_IN;

  f32x16 acc[4][2];
  #pragma unroll
  for (int mf=0;mf<4;++mf)
    #pragma unroll
    for (int nf=0;nf<2;++nf)
      #pragma unroll
      for (int r=0;r<16;++r) acc[mf][nf][r] = 0.f;

  s16x8 bvA[4][2], bvB[4][2];

  // prologue: A(0)->buf0, B(0)->bvA, A(1)->buf1; single full drain (once, cheap)
  SGA(0, 0);
  LOADB(0, bvA);
  SGA(1, 1);
  VM0; BAR;

  #pragma unroll 1
  for (int it=0; it<8; ++it){
    const int T = 2*it;
    SGA(T+1, 1);                    // T+1 <= 15 always
    LOADB(T+1, bvB);
    COMPUTE(0, bvA);
    VM0; BAR;
    if (it < 7){ SGA(T+2, 0); LOADB(T+2, bvA); }
    COMPUTE(1, bvB);
    VM0; BAR;
  }

  // epilogue: bias + relu + bf16 store.  C/D: col = lane&31, row = (r&3)+8*(r>>2)+4*l5
  const float b0v = b1c[col0 + wn*64 + l31];
  const float b1v = b1c[col0 + wn*64 + 32 + l31];
  #pragma unroll
  for (int mf=0;mf<4;++mf){
    const int rbase = row0 + wm*128 + mf*32 + 4*l5;
    #pragma unroll
    for (int nf=0;nf<2;++nf){
      const int col = col0 + wn*64 + nf*32 + l31;
      const float bias = nf ? b1v : b0v;
      #pragma unroll
      for (int r=0;r<16;++r){
        const int row = rbase + (r&3) + 8*(r>>2);
        float v = acc[mf][nf][r] + bias;
        v = v > 0.f ? v : 0.f;
        Hb[(size_t)row*NW1P + col] = f2bf(v);
      }
    }
  }
}

// ---------------- gates: softmax((relu-hidden) @ gW2 + gb2) ----------------
__global__ void gates_kernel(const u16* __restrict__ Hb, const float* __restrict__ gW2,
                             const float* __restrict__ gb2, float* __restrict__ gts)
{
  __shared__ float wsm[64*6];
  __shared__ float bsm[6];
  const int tid = threadIdx.x;
  const int bid = blockIdx.x;                 // 3 * 64 blocks
  const int g = bid >> 6;
  const int b = ((bid & 63) << 8) + tid;
  if (tid < 6) bsm[tid] = gb2[g*6 + tid];
  for (int i = tid; i < 384; i += 256) wsm[i] = gW2[g*384 + i];
  __syncthreads();
  const u16* gh = Hb + (size_t)b*NW1P + 2560 + g*64;
  float lg[6];
  #pragma unroll
  for (int e=0;e<6;++e) lg[e] = bsm[e];
  #pragma unroll
  for (int k8=0;k8<8;++k8){
    u16x8 hv = *(const u16x8*)&gh[k8*8];
    #pragma unroll
    for (int j=0;j<8;++j){
      const float h = bf2f(hv[j]);
      const int k = k8*8 + j;
      #pragma unroll
      for (int e=0;e<6;++e) lg[e] += h * wsm[k*6 + e];
    }
  }
  float mx = lg[0];
  #pragma unroll
  for (int e=1;e<6;++e) mx = fmaxf(mx, lg[e]);
  float s = 0.f; float p[6];
  #pragma unroll
  for (int e=0;e<6;++e){ p[e] = expf(lg[e]-mx); s += p[e]; }
  const float inv = 1.f / s;
  float* dst = gts + ((size_t)g*B_ROWS + b)*6;
  #pragma unroll
  for (int e=0;e<6;++e) dst[e] = p[e]*inv;
}

// ------- GEMM2 fused with gate-weighted combine -------
__global__ __launch_bounds__(256, 2) void gemm2_kernel(
    const u16* __restrict__ Hb, const u16* __restrict__ W2T,
    const float* __restrict__ b2c, const float* __restrict__ gts,
    float* __restrict__ outp)
{
  __shared__ __attribute__((aligned(16))) u16 lds[2][2][128*32];
  const int tid = threadIdx.x;
  const int lane = tid & 63;
  const int wid = tid >> 6;
  const int wm = wid >> 1, wn = wid & 1;
  const int bid = blockIdx.x;                 // 128 * 3
  const int mt = bid / 3;
  const int g  = bid - mt*3;
  const int row0 = mt*128;

  const int sr = tid >> 2;
  const int sk = (tid & 3) << 3;

  const f32x4 fz = {0.f,0.f,0.f,0.f};
  f32x4 oacc[4][4], eacc[4][4];
  #pragma unroll
  for (int m=0;m<4;++m)
    #pragma unroll
    for (int n=0;n<4;++n){ oacc[m][n] = fz; eacc[m][n] = fz; }

  auto stage = [&](int s, int buf){
    const int e  = s >> 3;
    const int ks = s & 7;
    const int eidv = (e < 4) ? e : (g*2 + e);
    const u16* ga = Hb  + (size_t)(row0 + sr)*NW1P + eidv*256 + ks*32 + sk;
    const u16* gb = W2T + (size_t)eidv*32768 + (size_t)sr*256 + ks*32 + sk;
    u16* la = &lds[buf][0][tid*8];
    u16* lb = &lds[buf][1][tid*8];
    #pragma unroll
    for (int j=0;j<2;++j){
      gload_lds16(ga + (size_t)j*64*NW1P, la + j*2048);
      gload_lds16(gb + (size_t)j*64*256,  lb + j*2048);
    }
  };

  const int fr = lane & 15;
  const int ko = (lane >> 4) << 3;
  const int r4 = (lane >> 4) << 2;

  stage(0, 0);
  __syncthreads();

  for (int s=0; s<48; ++s){
    const int buf = s & 1;
    if (s+1 < 48) stage(s+1, buf^1);
    s16x8 af[4], bfv[4];
    #pragma unroll
    for (int m=0;m<4;++m)
      af[m] = *(const s16x8*)&lds[buf][0][(wm*64 + m*16 + fr)*32 + ko];
    #pragma unroll
    for (int n=0;n<4;++n)
      bfv[n] = *(const s16x8*)&lds[buf][1][(wn*64 + n*16 + fr)*32 + ko];
    #pragma unroll
    for (int m=0;m<4;++m)
      #pragma unroll
      for (int n=0;n<4;++n)
        eacc[m][n] = __builtin_amdgcn_mfma_f32_16x16x32_bf16(af[m], bfv[n], eacc[m][n], 0, 0, 0);
    if ((s & 7) == 7){
      const int e = s >> 3;
      const int eidv = (e < 4) ? e : (g*2 + e);
      #pragma unroll
      for (int m=0;m<4;++m){
        const int lr = wm*64 + m*16 + r4;
        float w[4];
        #pragma unroll
        for (int r=0;r<4;++r)
          w[r] = gts[((size_t)g*B_ROWS + row0 + lr + r)*6 + e];
        #pragma unroll
        for (int n=0;n<4;++n){
          const int c = wn*64 + n*16 + fr;
          const float bias = b2c[eidv*128 + c];
          #pragma unroll
          for (int r=0;r<4;++r){
            float v = eacc[m][n][r] + bias;
            v = v > 0.f ? v : 0.f;
            oacc[m][n][r] += w[r]*v;
          }
          eacc[m][n] = fz;
        }
      }
    }
    __syncthreads();
  }

  #pragma unroll
  for (int m=0;m<4;++m){
    const int lr = wm*64 + m*16 + r4;
    #pragma unroll
    for (int n=0;n<4;++n){
      const int c = wn*64 + n*16 + fr;
      #pragma unroll
      for (int r=0;r<4;++r)
        outp[((size_t)g*B_ROWS + row0 + lr + r)*H2N + c] = oacc[m][n][r];
    }
  }
}

extern "C" void kernel_launch(void* const* d_in, const int* in_sizes, int n_in,
                              void* d_out, int out_size, void* d_ws, size_t ws_size,
                              hipStream_t stream)
{
  (void)in_sizes; (void)n_in; (void)out_size; (void)ws_size;
  const float* x   = (const float*)d_in[0];
  const float* sW1 = (const float*)d_in[2];
  const float* sb1 = (const float*)d_in[3];
  const float* sW2 = (const float*)d_in[4];
  const float* sb2 = (const float*)d_in[5];
  const float* dW1 = (const float*)d_in[6];
  const float* db1 = (const float*)d_in[7];
  const float* dW2 = (const float*)d_in[8];
  const float* db2 = (const float*)d_in[9];
  const float* gW1 = (const float*)d_in[10];
  const float* gb1 = (const float*)d_in[11];
  const float* gW2 = (const float*)d_in[12];
  const float* gb2 = (const float*)d_in[13];
  float* outp = (float*)d_out;

  char* ws = (char*)d_ws;
  u16*   Xb  = (u16*  )(ws + 0);          // 16384*1024*2      = 33554432
  u16*   W1T = (u16*  )(ws + 33554432);   // 2816*1024*2       =  5767168
  float* b1c = (float*)(ws + 39321600);   // 2816*4            =    11264
  u16*   W2T = (u16*  )(ws + 39332864);   // 10*128*256*2      =   655360
  float* b2c = (float*)(ws + 39988224);   // 10*128*4          =     5120
  float* gts = (float*)(ws + 39993344);   // 3*16384*6*4       =  1179648
  u16*   Hb  = (u16*  )(ws + 41172992);   // 16384*2816*2      = 92274688  (end ~133.4 MB)

  pack_w1_kernel<<<dim3(704),  dim3(256), 0, stream>>>(sW1,dW1,gW1,sb1,db1,gb1,W1T,b1c);
  pack_w2_kernel<<<dim3(80),   dim3(256), 0, stream>>>(sW2,dW2,sb2,db2,W2T,b2c);
  cast_x_kernel <<<dim3(8192), dim3(256), 0, stream>>>(x, Xb);
  gemm1_kernel  <<<dim3(704),  dim3(512), 0, stream>>>(Xb, W1T, b1c, Hb);
  gates_kernel  <<<dim3(192),  dim3(256), 0, stream>>>(Hb, gW2, gb2, gts);
  gemm2_kernel  <<<dim3(384),  dim3(256), 0, stream>>>(Hb, W2T, b2c, gts, outp);
}

// Round 7
// 175.260 us; speedup vs baseline: 11.3503x; 1.2425x over previous
//
#include <hip/hip_runtime.h>

#define B_ROWS 16384
#define D_IN   1024
#define NW1P   2816   // padded GEMM1 N: 10*256 expert + 3*64 gate + 64 pad
#define H2N    128

typedef unsigned short u16;
typedef __attribute__((ext_vector_type(4)))  float f32x4;
typedef __attribute__((ext_vector_type(16))) float f32x16;
typedef __attribute__((ext_vector_type(8)))  short s16x8;
typedef __attribute__((ext_vector_type(8)))  unsigned short u16x8;

__device__ __forceinline__ u16 f2bf(float f){
  unsigned int u = __float_as_uint(f);
  u += 0x7FFFu + ((u >> 16) & 1u);
  return (u16)(u >> 16);
}
__device__ __forceinline__ float bf2f(u16 h){
  return __uint_as_float(((unsigned int)h) << 16);
}

// async global->LDS, 16B per lane. LDS dest must be linear (wave base + lane*16).
__device__ __forceinline__ void gload_lds16(const void* gp, void* lp){
  typedef __attribute__((address_space(1))) unsigned int GUI;
  typedef __attribute__((address_space(3))) unsigned int LUI;
  __builtin_amdgcn_global_load_lds((GUI*)(unsigned long long)gp,
                                   (LUI*)(unsigned int)(unsigned long long)lp,
                                   16, 0, 0);
}

// ---------------- weight packing ----------------
// W1F: MFMA-fragment-packed B operand for 32x32x16.
// W1F[((n32*64 + k16)*64 + lane)*8 + j] = W1(d,n) with col=n32*32+(lane&31),
// k = k16*16 + (lane>>5)*8 + j.  A wave's B-fragment load is then 64 lanes x 16B
// CONTIGUOUS (1KB) -- fully coalesced, no LDS needed for B.
__global__ void pack_w1_kernel(const float* __restrict__ sW1, const float* __restrict__ dW1,
                               const float* __restrict__ gW1, const float* __restrict__ sb1,
                               const float* __restrict__ db1, const float* __restrict__ gb1,
                               u16* __restrict__ W1F, float* __restrict__ b1c)
{
  __shared__ float t[64*65];
  const int tid = threadIdx.x;
  const int bid = blockIdx.x;          // 44 * 16
  const int ntile = bid >> 4, dtile = bid & 15;
  const int n0 = ntile*64, d0 = dtile*64;
  #pragma unroll
  for (int i=0;i<16;++i){
    int idx = i*256 + tid;
    int dd = idx >> 6, nn = idx & 63;
    int n = n0 + nn, d = d0 + dd;
    float v;
    if (n < 2560){
      int e = n >> 8, h = n & 255;
      v = (e < 4) ? sW1[((size_t)e*D_IN + d)*256 + h]
                  : dW1[((size_t)(e-4)*D_IN + d)*256 + h];
    } else if (n < 2752){
      int t2 = n - 2560; int gg = t2 >> 6, k = t2 & 63;
      v = gW1[((size_t)gg*D_IN + d)*64 + k];
    } else v = 0.f;
    t[nn*65 + dd] = v;
  }
  __syncthreads();
  #pragma unroll
  for (int i=0;i<16;++i){
    int idx = i*256 + tid;
    int nn = idx >> 6, dd = idx & 63;
    const int n = n0 + nn, d = d0 + dd;
    const int lane = ((d >> 3) & 1)*32 + (n & 31);
    const size_t di = (((size_t)(n >> 5)*64 + (d >> 4))*64 + lane)*8 + (d & 7);
    W1F[di] = f2bf(t[nn*65 + dd]);
  }
  if (dtile == 0 && tid < 64){
    int n = n0 + tid; float v;
    if (n < 2560){ int e = n>>8, h = n&255; v = (e<4)? sb1[e*256+h] : db1[(e-4)*256+h]; }
    else if (n < 2752){ int t2 = n-2560; v = gb1[(t2>>6)*64 + (t2&63)]; }
    else v = 0.f;
    b1c[n] = v;
  }
}

__global__ void pack_w2_kernel(const float* __restrict__ sW2, const float* __restrict__ dW2,
                               const float* __restrict__ sb2, const float* __restrict__ db2,
                               u16* __restrict__ W2T, float* __restrict__ b2c)
{
  __shared__ float t[64*65];
  const int tid = threadIdx.x;
  const int bid = blockIdx.x;          // 10 * 2 * 4
  const int e = bid >> 3, ot = (bid >> 2) & 1, ht = bid & 3;
  const int o0 = ot*64, h0 = ht*64;
  #pragma unroll
  for (int i=0;i<16;++i){
    int idx = i*256 + tid;
    int hh = idx >> 6, oo = idx & 63;
    float v = (e < 4) ? sW2[((size_t)e*256 + h0+hh)*128 + o0+oo]
                      : dW2[((size_t)(e-4)*256 + h0+hh)*128 + o0+oo];
    t[oo*65 + hh] = v;
  }
  __syncthreads();
  #pragma unroll
  for (int i=0;i<16;++i){
    int idx = i*256 + tid;
    int oo = idx >> 6, hh = idx & 63;
    W2T[(size_t)e*32768 + (size_t)(o0+oo)*256 + h0 + hh] = f2bf(t[oo*65 + hh]);
  }
  if (ht == 0 && ot == 0 && tid < 128)
    b2c[e*128 + tid] = (e < 4) ? sb2[e*128 + tid] : db2[(e-4)*128 + tid];
}

__global__ void cast_x_kernel(const float* __restrict__ x, u16* __restrict__ xb)
{
  const size_t i = ((size_t)blockIdx.x*256 + threadIdx.x)*8;
  f32x4 a = *(const f32x4*)(x + i);
  f32x4 b = *(const f32x4*)(x + i + 4);
  u16x8 r;
  r[0]=f2bf(a[0]); r[1]=f2bf(a[1]); r[2]=f2bf(a[2]); r[3]=f2bf(a[3]);
  r[4]=f2bf(b[0]); r[5]=f2bf(b[1]); r[6]=f2bf(b[2]); r[7]=f2bf(b[3]);
  *(u16x8*)(xb + i) = r;
}

// ---------------- GEMM1: 256x256 tile, BK=64, 32x32x16 MFMA ----------------
// A staged in LDS (2 x 32 KB dbuf); B loaded global->reg from fragment-packed W1F
// (fully coalesced 1KB/load), double-buffered bvA/bvB. LDS/K-tile = 160 KB (~1430
// cyc) < MFMA 2048 cyc -> LDS not the binding pipe. One vmcnt(0)+barrier per tile.

#define VM0 asm volatile("s_waitcnt vmcnt(0)" ::: "memory")
#define BAR __builtin_amdgcn_s_barrier()

#define SGA(T, BUF) do{ \
  const u16* ga_ = aStg + (T)*64; \
  _Pragma("unroll") for (int j=0;j<4;++j) \
    gload_lds16(ga_ + j*65536, &L[BUF][j*4096 + tid*8]); \
}while(0)

// W1F block: n32 block = 32768 u16; k16 step = 512 u16; lane offset folded in pB.
#define LOADB(T, BV) do{ \
  _Pragma("unroll") for (int kk=0;kk<4;++kk){ \
    BV[kk][0] = *(const s16x8*)(pB0 + ((T)*4 + kk)*512); \
    BV[kk][1] = *(const s16x8*)(pB1 + ((T)*4 + kk)*512); \
  } \
}while(0)

#define COMPUTE(BUF, BV) do{ \
  _Pragma("unroll") for (int kk=0;kk<4;++kk){ \
    s16x8 av[4]; \
    _Pragma("unroll") for (int mf=0;mf<4;++mf){ \
      const int row_ = wm*128 + mf*32 + l31; \
      av[mf] = *(const s16x8*)&L[BUF][(row_<<6) + (((((kk<<1)|l5)) ^ (row_&7))<<3)]; \
    } \
    __builtin_amdgcn_s_setprio(1); \
    _Pragma("unroll") for (int mf=0;mf<4;++mf){ \
      acc[mf][0] = __builtin_amdgcn_mfma_f32_32x32x16_bf16(av[mf], BV[kk][0], acc[mf][0], 0, 0, 0); \
      acc[mf][1] = __builtin_amdgcn_mfma_f32_32x32x16_bf16(av[mf], BV[kk][1], acc[mf][1], 0, 0, 0); \
    } \
    __builtin_amdgcn_s_setprio(0); \
  } \
}while(0)

__global__ __launch_bounds__(512, 2) void gemm1_kernel(
    const u16* __restrict__ Xb, const u16* __restrict__ W1F,
    const float* __restrict__ b1c, u16* __restrict__ Hb)
{
  __shared__ __attribute__((aligned(16))) u16 L[2][16384];   // A only: 2 x 32 KB
  const int tid  = threadIdx.x;
  const int lane = tid & 63;
  const int wid  = tid >> 6;
  const int wm   = wid >> 2;          // 0..1
  const int wn   = wid & 3;           // 0..3

  // 704 blocks = 64 mt x 11 nt. Per-XCD: mt-fast (8 A panels = 4 MB L2-resident),
  // nt slow (B strip 512 KB hot for 8 consecutive blocks).
  const int bid = blockIdx.x;
  const int xcd = bid & 7, pos = bid >> 3;        // pos 0..87
  const int mt  = xcd*8 + (pos & 7);              // 0..63
  const int nt  = pos >> 3;                       // 0..10
  const int row0 = mt*256, col0 = nt*256;

  const int l31 = lane & 31, l5 = lane >> 5;

  // A staging: thread -> row (tid>>3), phys slot (tid&7); pre-swizzled source
  // slot = (tid&7) ^ ((tid>>3)&7)
  const int sRow = tid >> 3;
  const int sSl  = (tid & 7) ^ (sRow & 7);
  const u16* aStg = Xb + (size_t)(row0 + sRow)*D_IN + sSl*8;

  // B fragment pointers: wave (wn) owns n32 blocks nt*8 + wn*2 + {0,1}
  const u16* pB0 = W1F + ((size_t)(nt*8 + wn*2)*32768) + lane*8;
  const u16* pB1 = pB0 + 32768;

  f32x16 acc[4][2];
  #pragma unroll
  for (int mf=0;mf<4;++mf)
    #pragma unroll
    for (int nf=0;nf<2;++nf)
      #pragma unroll
      for (int r=0;r<16;++r) acc[mf][nf][r] = 0.f;

  s16x8 bvA[4][2], bvB[4][2];

  // prologue
  SGA(0, 0);
  LOADB(0, bvA);
  SGA(1, 1);
  VM0; BAR;

  #pragma unroll 1
  for (int it=0; it<8; ++it){
    const int T = 2*it;
    SGA(T+1, 1);                    // T+1 <= 15 always
    LOADB(T+1, bvB);
    COMPUTE(0, bvA);
    VM0; BAR;
    if (it < 7){ SGA(T+2, 0); LOADB(T+2, bvA); }
    COMPUTE(1, bvB);
    VM0; BAR;
  }

  // epilogue: bias + relu + bf16 store.  C/D: col = lane&31, row = (r&3)+8*(r>>2)+4*l5
  const float b0v = b1c[col0 + wn*64 + l31];
  const float b1v = b1c[col0 + wn*64 + 32 + l31];
  #pragma unroll
  for (int mf=0;mf<4;++mf){
    const int rbase = row0 + wm*128 + mf*32 + 4*l5;
    #pragma unroll
    for (int nf=0;nf<2;++nf){
      const int col = col0 + wn*64 + nf*32 + l31;
      const float bias = nf ? b1v : b0v;
      #pragma unroll
      for (int r=0;r<16;++r){
        const int row = rbase + (r&3) + 8*(r>>2);
        float v = acc[mf][nf][r] + bias;
        v = v > 0.f ? v : 0.f;
        Hb[(size_t)row*NW1P + col] = f2bf(v);
      }
    }
  }
}

// ---------------- gates: softmax((relu-hidden) @ gW2 + gb2) ----------------
__global__ void gates_kernel(const u16* __restrict__ Hb, const float* __restrict__ gW2,
                             const float* __restrict__ gb2, float* __restrict__ gts)
{
  __shared__ float wsm[64*6];
  __shared__ float bsm[6];
  const int tid = threadIdx.x;
  const int bid = blockIdx.x;                 // 3 * 64 blocks
  const int g = bid >> 6;
  const int b = ((bid & 63) << 8) + tid;
  if (tid < 6) bsm[tid] = gb2[g*6 + tid];
  for (int i = tid; i < 384; i += 256) wsm[i] = gW2[g*384 + i];
  __syncthreads();
  const u16* gh = Hb + (size_t)b*NW1P + 2560 + g*64;
  float lg[6];
  #pragma unroll
  for (int e=0;e<6;++e) lg[e] = bsm[e];
  #pragma unroll
  for (int k8=0;k8<8;++k8){
    u16x8 hv = *(const u16x8*)&gh[k8*8];
    #pragma unroll
    for (int j=0;j<8;++j){
      const float h = bf2f(hv[j]);
      const int k = k8*8 + j;
      #pragma unroll
      for (int e=0;e<6;++e) lg[e] += h * wsm[k*6 + e];
    }
  }
  float mx = lg[0];
  #pragma unroll
  for (int e=1;e<6;++e) mx = fmaxf(mx, lg[e]);
  float s = 0.f; float p[6];
  #pragma unroll
  for (int e=0;e<6;++e){ p[e] = expf(lg[e]-mx); s += p[e]; }
  const float inv = 1.f / s;
  float* dst = gts + ((size_t)g*B_ROWS + b)*6;
  #pragma unroll
  for (int e=0;e<6;++e) dst[e] = p[e]*inv;
}

// ------- GEMM2 fused with gate-weighted combine -------
__global__ __launch_bounds__(256, 2) void gemm2_kernel(
    const u16* __restrict__ Hb, const u16* __restrict__ W2T,
    const float* __restrict__ b2c, const float* __restrict__ gts,
    float* __restrict__ outp)
{
  __shared__ __attribute__((aligned(16))) u16 lds[2][2][128*32];
  const int tid = threadIdx.x;
  const int lane = tid & 63;
  const int wid = tid >> 6;
  const int wm = wid >> 1, wn = wid & 1;
  const int bid = blockIdx.x;                 // 128 * 3
  const int mt = bid / 3;
  const int g  = bid - mt*3;
  const int row0 = mt*128;

  const int sr = tid >> 2;
  const int sk = (tid & 3) << 3;

  const f32x4 fz = {0.f,0.f,0.f,0.f};
  f32x4 oacc[4][4], eacc[4][4];
  #pragma unroll
  for (int m=0;m<4;++m)
    #pragma unroll
    for (int n=0;n<4;++n){ oacc[m][n] = fz; eacc[m][n] = fz; }

  auto stage = [&](int s, int buf){
    const int e  = s >> 3;
    const int ks = s & 7;
    const int eidv = (e < 4) ? e : (g*2 + e);
    const u16* ga = Hb  + (size_t)(row0 + sr)*NW1P + eidv*256 + ks*32 + sk;
    const u16* gb = W2T + (size_t)eidv*32768 + (size_t)sr*256 + ks*32 + sk;
    u16* la = &lds[buf][0][tid*8];
    u16* lb = &lds[buf][1][tid*8];
    #pragma unroll
    for (int j=0;j<2;++j){
      gload_lds16(ga + (size_t)j*64*NW1P, la + j*2048);
      gload_lds16(gb + (size_t)j*64*256,  lb + j*2048);
    }
  };

  const int fr = lane & 15;
  const int ko = (lane >> 4) << 3;
  const int r4 = (lane >> 4) << 2;

  stage(0, 0);
  __syncthreads();

  for (int s=0; s<48; ++s){
    const int buf = s & 1;
    if (s+1 < 48) stage(s+1, buf^1);
    s16x8 af[4], bfv[4];
    #pragma unroll
    for (int m=0;m<4;++m)
      af[m] = *(const s16x8*)&lds[buf][0][(wm*64 + m*16 + fr)*32 + ko];
    #pragma unroll
    for (int n=0;n<4;++n)
      bfv[n] = *(const s16x8*)&lds[buf][1][(wn*64 + n*16 + fr)*32 + ko];
    #pragma unroll
    for (int m=0;m<4;++m)
      #pragma unroll
      for (int n=0;n<4;++n)
        eacc[m][n] = __builtin_amdgcn_mfma_f32_16x16x32_bf16(af[m], bfv[n], eacc[m][n], 0, 0, 0);
    if ((s & 7) == 7){
      const int e = s >> 3;
      const int eidv = (e < 4) ? e : (g*2 + e);
      #pragma unroll
      for (int m=0;m<4;++m){
        const int lr = wm*64 + m*16 + r4;
        float w[4];
        #pragma unroll
        for (int r=0;r<4;++r)
          w[r] = gts[((size_t)g*B_ROWS + row0 + lr + r)*6 + e];
        #pragma unroll
        for (int n=0;n<4;++n){
          const int c = wn*64 + n*16 + fr;
          const float bias = b2c[eidv*128 + c];
          #pragma unroll
          for (int r=0;r<4;++r){
            float v = eacc[m][n][r] + bias;
            v = v > 0.f ? v : 0.f;
            oacc[m][n][r] += w[r]*v;
          }
          eacc[m][n] = fz;
        }
      }
    }
    __syncthreads();
  }

  #pragma unroll
  for (int m=0;m<4;++m){
    const int lr = wm*64 + m*16 + r4;
    #pragma unroll
    for (int n=0;n<4;++n){
      const int c = wn*64 + n*16 + fr;
      #pragma unroll
      for (int r=0;r<4;++r)
        outp[((size_t)g*B_ROWS + row0 + lr + r)*H2N + c] = oacc[m][n][r];
    }
  }
}

extern "C" void kernel_launch(void* const* d_in, const int* in_sizes, int n_in,
                              void* d_out, int out_size, void* d_ws, size_t ws_size,
                              hipStream_t stream)
{
  (void)in_sizes; (void)n_in; (void)out_size; (void)ws_size;
  const float* x   = (const float*)d_in[0];
  const float* sW1 = (const float*)d_in[2];
  const float* sb1 = (const float*)d_in[3];
  const float* sW2 = (const float*)d_in[4];
  const float* sb2 = (const float*)d_in[5];
  const float* dW1 = (const float*)d_in[6];
  const float* db1 = (const float*)d_in[7];
  const float* dW2 = (const float*)d_in[8];
  const float* db2 = (const float*)d_in[9];
  const float* gW1 = (const float*)d_in[10];
  const float* gb1 = (const float*)d_in[11];
  const float* gW2 = (const float*)d_in[12];
  const float* gb2 = (const float*)d_in[13];
  float* outp = (float*)d_out;

  char* ws = (char*)d_ws;
  u16*   Xb  = (u16*  )(ws + 0);          // 16384*1024*2      = 33554432
  u16*   W1F = (u16*  )(ws + 33554432);   // 88*64*64*8*2      =  5767168
  float* b1c = (float*)(ws + 39321600);   // 2816*4            =    11264
  u16*   W2T = (u16*  )(ws + 39332864);   // 10*128*256*2      =   655360
  float* b2c = (float*)(ws + 39988224);   // 10*128*4          =     5120
  float* gts = (float*)(ws + 39993344);   // 3*16384*6*4       =  1179648
  u16*   Hb  = (u16*  )(ws + 41172992);   // 16384*2816*2      = 92274688  (end ~133.4 MB)

  pack_w1_kernel<<<dim3(704),  dim3(256), 0, stream>>>(sW1,dW1,gW1,sb1,db1,gb1,W1F,b1c);
  pack_w2_kernel<<<dim3(80),   dim3(256), 0, stream>>>(sW2,dW2,sb2,db2,W2T,b2c);
  cast_x_kernel <<<dim3(8192), dim3(256), 0, stream>>>(x, Xb);
  gemm1_kernel  <<<dim3(704),  dim3(512), 0, stream>>>(Xb, W1F, b1c, Hb);
  gates_kernel  <<<dim3(192),  dim3(256), 0, stream>>>(Hb, gW2, gb2, gts);
  gemm2_kernel  <<<dim3(384),  dim3(256), 0, stream>>>(Hb, W2T, b2c, gts, outp);
}

// Round 8
// 169.098 us; speedup vs baseline: 11.7639x; 1.0364x over previous
//
#include <hip/hip_runtime.h>

#define B_ROWS 16384
#define D_IN   1024
#define NW1P   2816   // padded GEMM1 N: 10*256 expert + 3*64 gate + 64 pad
#define H2N    128

typedef unsigned short u16;
typedef __attribute__((ext_vector_type(4)))  float f32x4;
typedef __attribute__((ext_vector_type(16))) float f32x16;
typedef __attribute__((ext_vector_type(8)))  short s16x8;
typedef __attribute__((ext_vector_type(8)))  unsigned short u16x8;

__device__ __forceinline__ u16 f2bf(float f){
  unsigned int u = __float_as_uint(f);
  u += 0x7FFFu + ((u >> 16) & 1u);
  return (u16)(u >> 16);
}
__device__ __forceinline__ float bf2f(u16 h){
  return __uint_as_float(((unsigned int)h) << 16);
}

// async global->LDS, 16B per lane. LDS dest must be linear (wave base + lane*16).
__device__ __forceinline__ void gload_lds16(const void* gp, void* lp){
  typedef __attribute__((address_space(1))) unsigned int GUI;
  typedef __attribute__((address_space(3))) unsigned int LUI;
  __builtin_amdgcn_global_load_lds((GUI*)(unsigned long long)gp,
                                   (LUI*)(unsigned int)(unsigned long long)lp,
                                   16, 0, 0);
}

// ---------------- weight packing ----------------
// W1F: MFMA-fragment-packed B operand for 32x32x16.
// W1F[((n32*64 + k16)*64 + lane)*8 + j] = W1(d,n), col=n32*32+(lane&31),
// k = k16*16 + (lane>>5)*8 + j.  Wave B-frag load = 64 lanes x 16B contiguous.
__global__ void pack_w1_kernel(const float* __restrict__ sW1, const float* __restrict__ dW1,
                               const float* __restrict__ gW1, const float* __restrict__ sb1,
                               const float* __restrict__ db1, const float* __restrict__ gb1,
                               u16* __restrict__ W1F, float* __restrict__ b1c)
{
  __shared__ float t[64*65];
  const int tid = threadIdx.x;
  const int bid = blockIdx.x;          // 44 * 16
  const int ntile = bid >> 4, dtile = bid & 15;
  const int n0 = ntile*64, d0 = dtile*64;
  #pragma unroll
  for (int i=0;i<16;++i){
    int idx = i*256 + tid;
    int dd = idx >> 6, nn = idx & 63;
    int n = n0 + nn, d = d0 + dd;
    float v;
    if (n < 2560){
      int e = n >> 8, h = n & 255;
      v = (e < 4) ? sW1[((size_t)e*D_IN + d)*256 + h]
                  : dW1[((size_t)(e-4)*D_IN + d)*256 + h];
    } else if (n < 2752){
      int t2 = n - 2560; int gg = t2 >> 6, k = t2 & 63;
      v = gW1[((size_t)gg*D_IN + d)*64 + k];
    } else v = 0.f;
    t[nn*65 + dd] = v;
  }
  __syncthreads();
  #pragma unroll
  for (int i=0;i<16;++i){
    int idx = i*256 + tid;
    int nn = idx >> 6, dd = idx & 63;
    const int n = n0 + nn, d = d0 + dd;
    const int lane = ((d >> 3) & 1)*32 + (n & 31);
    const size_t di = (((size_t)(n >> 5)*64 + (d >> 4))*64 + lane)*8 + (d & 7);
    W1F[di] = f2bf(t[nn*65 + dd]);
  }
  if (dtile == 0 && tid < 64){
    int n = n0 + tid; float v;
    if (n < 2560){ int e = n>>8, h = n&255; v = (e<4)? sb1[e*256+h] : db1[(e-4)*256+h]; }
    else if (n < 2752){ int t2 = n-2560; v = gb1[(t2>>6)*64 + (t2&63)]; }
    else v = 0.f;
    b1c[n] = v;
  }
}

// W2F: fragment-packed W2 for 32x32x16 B operand.
// W2F[(((e*4 + n32)*16 + k16)*64 + lane)*8 + j] = W2[e][k][c],
// k = k16*16 + (lane>>5)*8 + j, c = n32*32 + (lane&31).
__global__ void pack_w2_kernel(const float* __restrict__ sW2, const float* __restrict__ dW2,
                               const float* __restrict__ sb2, const float* __restrict__ db2,
                               u16* __restrict__ W2F, float* __restrict__ b2c)
{
  const int tid = threadIdx.x;
  const int bid = blockIdx.x;          // 160 = 10 experts * 16
  const int e   = bid >> 4;
  const int sub = (bid & 15)*256 + tid;   // 0..4095
  const int n32 = sub >> 10, k16 = (sub >> 6) & 15, lane = sub & 63;
  const int c   = n32*32 + (lane & 31);
  const int kb  = k16*16 + (lane >> 5)*8;
  u16 out[8];
  #pragma unroll
  for (int j=0;j<8;++j){
    const int k = kb + j;
    float v = (e < 4) ? sW2[((size_t)e*256 + k)*128 + c]
                      : dW2[((size_t)(e-4)*256 + k)*128 + c];
    out[j] = f2bf(v);
  }
  *(u16x8*)&W2F[(size_t)e*32768 + (size_t)sub*8] = *(u16x8*)out;
  if ((bid & 15) == 0 && tid < 128)
    b2c[e*128 + tid] = (e < 4) ? sb2[e*128 + tid] : db2[(e-4)*128 + tid];
}

__global__ void cast_x_kernel(const float* __restrict__ x, u16* __restrict__ xb)
{
  const size_t i = ((size_t)blockIdx.x*256 + threadIdx.x)*8;
  f32x4 a = *(const f32x4*)(x + i);
  f32x4 b = *(const f32x4*)(x + i + 4);
  u16x8 r;
  r[0]=f2bf(a[0]); r[1]=f2bf(a[1]); r[2]=f2bf(a[2]); r[3]=f2bf(a[3]);
  r[4]=f2bf(b[0]); r[5]=f2bf(b[1]); r[6]=f2bf(b[2]); r[7]=f2bf(b[3]);
  *(u16x8*)(xb + i) = r;
}

// ---------------- GEMM1: 256x256 tile, BK=64, 32x32x16 MFMA ----------------
// A staged in LDS (2 x 32 KB dbuf); B global->reg from fragment-packed W1F.
// COUNTED vmcnt(8): per half-phase issue {SGA(4 gld_lds), LOADB(8 b128)}, compute,
// then wait only the 4 OLDEST (the SGA) -- the 8 B-loads stay in flight across the
// barrier (T4, m218). Never drains to 0 in the main loop.

#define W8  asm volatile("s_waitcnt vmcnt(8)" ::: "memory")
#define W4  asm volatile("s_waitcnt vmcnt(4)" ::: "memory")
#define VM0 asm volatile("s_waitcnt vmcnt(0)" ::: "memory")
#define BAR __builtin_amdgcn_s_barrier()

#define SGA(T, BUF) do{ \
  const u16* ga_ = aStg + (T)*64; \
  _Pragma("unroll") for (int j=0;j<4;++j) \
    gload_lds16(ga_ + j*65536, &L[BUF][j*4096 + tid*8]); \
}while(0)

#define LOADB(T, BV) do{ \
  _Pragma("unroll") for (int kk=0;kk<4;++kk){ \
    BV[kk][0] = *(const s16x8*)(pB0 + ((T)*4 + kk)*512); \
    BV[kk][1] = *(const s16x8*)(pB1 + ((T)*4 + kk)*512); \
  } \
}while(0)

#define COMPUTE(BUF, BV) do{ \
  _Pragma("unroll") for (int kk=0;kk<4;++kk){ \
    s16x8 av[4]; \
    _Pragma("unroll") for (int mf=0;mf<4;++mf){ \
      const int row_ = wm*128 + mf*32 + l31; \
      av[mf] = *(const s16x8*)&L[BUF][(row_<<6) + (((((kk<<1)|l5)) ^ (row_&7))<<3)]; \
    } \
    __builtin_amdgcn_s_setprio(1); \
    _Pragma("unroll") for (int mf=0;mf<4;++mf){ \
      acc[mf][0] = __builtin_amdgcn_mfma_f32_32x32x16_bf16(av[mf], BV[kk][0], acc[mf][0], 0, 0, 0); \
      acc[mf][1] = __builtin_amdgcn_mfma_f32_32x32x16_bf16(av[mf], BV[kk][1], acc[mf][1], 0, 0, 0); \
    } \
    __builtin_amdgcn_s_setprio(0); \
  } \
}while(0)

__global__ __launch_bounds__(512, 2) void gemm1_kernel(
    const u16* __restrict__ Xb, const u16* __restrict__ W1F,
    const float* __restrict__ b1c, u16* __restrict__ Hb)
{
  __shared__ __attribute__((aligned(16))) u16 L[2][16384];   // A only: 2 x 32 KB
  const int tid  = threadIdx.x;
  const int lane = tid & 63;
  const int wid  = tid >> 6;
  const int wm   = wid >> 2;          // 0..1
  const int wn   = wid & 3;           // 0..3

  // 704 blocks = 64 mt x 11 nt; per XCD mt-fast (8 A panels cycle in L2).
  const int bid = blockIdx.x;
  const int xcd = bid & 7, pos = bid >> 3;
  const int mt  = xcd*8 + (pos & 7);
  const int nt  = pos >> 3;
  const int row0 = mt*256, col0 = nt*256;

  const int l31 = lane & 31, l5 = lane >> 5;

  const int sRow = tid >> 3;
  const int sSl  = (tid & 7) ^ (sRow & 7);
  const u16* aStg = Xb + (size_t)(row0 + sRow)*D_IN + sSl*8;

  const u16* pB0 = W1F + ((size_t)(nt*8 + wn*2)*32768) + lane*8;
  const u16* pB1 = pB0 + 32768;

  f32x16 acc[4][2];
  #pragma unroll
  for (int mf=0;mf<4;++mf)
    #pragma unroll
    for (int nf=0;nf<2;++nf)
      #pragma unroll
      for (int r=0;r<16;++r) acc[mf][nf][r] = 0.f;

  s16x8 bvA[4][2], bvB[4][2];

  // prologue: tile 0 only (tile 1 staged in first loop half)
  SGA(0, 0);
  LOADB(0, bvA);
  VM0; BAR;

  #pragma unroll 1
  for (int it=0; it<8; ++it){
    const int T = 2*it;
    SGA(T+1, 1);                 // 4 gld_lds (oldest of this phase)
    LOADB(T+1, bvB);             // 8 b128 (newest, may stay in flight)
    COMPUTE(0, bvA);
    W8; BAR;                     // waits SGA(T+1) only
    if (it < 7){ SGA(T+2, 0); LOADB(T+2, bvA); }
    COMPUTE(1, bvB);
    W8; BAR;
  }

  // epilogue: bias + relu + bf16 store.  C/D: col = lane&31, row = (r&3)+8*(r>>2)+4*l5
  const float b0v = b1c[col0 + wn*64 + l31];
  const float b1v = b1c[col0 + wn*64 + 32 + l31];
  #pragma unroll
  for (int mf=0;mf<4;++mf){
    const int rbase = row0 + wm*128 + mf*32 + 4*l5;
    #pragma unroll
    for (int nf=0;nf<2;++nf){
      const int col = col0 + wn*64 + nf*32 + l31;
      const float bias = nf ? b1v : b0v;
      #pragma unroll
      for (int r=0;r<16;++r){
        const int row = rbase + (r&3) + 8*(r>>2);
        float v = acc[mf][nf][r] + bias;
        v = v > 0.f ? v : 0.f;
        Hb[(size_t)row*NW1P + col] = f2bf(v);
      }
    }
  }
}

// ---------------- gates: softmax((relu-hidden) @ gW2 + gb2) ----------------
__global__ void gates_kernel(const u16* __restrict__ Hb, const float* __restrict__ gW2,
                             const float* __restrict__ gb2, float* __restrict__ gts)
{
  __shared__ float wsm[64*6];
  __shared__ float bsm[6];
  const int tid = threadIdx.x;
  const int bid = blockIdx.x;                 // 3 * 64 blocks
  const int g = bid >> 6;
  const int b = ((bid & 63) << 8) + tid;
  if (tid < 6) bsm[tid] = gb2[g*6 + tid];
  for (int i = tid; i < 384; i += 256) wsm[i] = gW2[g*384 + i];
  __syncthreads();
  const u16* gh = Hb + (size_t)b*NW1P + 2560 + g*64;
  float lg[6];
  #pragma unroll
  for (int e=0;e<6;++e) lg[e] = bsm[e];
  #pragma unroll
  for (int k8=0;k8<8;++k8){
    u16x8 hv = *(const u16x8*)&gh[k8*8];
    #pragma unroll
    for (int j=0;j<8;++j){
      const float h = bf2f(hv[j]);
      const int k = k8*8 + j;
      #pragma unroll
      for (int e=0;e<6;++e) lg[e] += h * wsm[k*6 + e];
    }
  }
  float mx = lg[0];
  #pragma unroll
  for (int e=1;e<6;++e) mx = fmaxf(mx, lg[e]);
  float s = 0.f; float p[6];
  #pragma unroll
  for (int e=0;e<6;++e){ p[e] = expf(lg[e]-mx); s += p[e]; }
  const float inv = 1.f / s;
  float* dst = gts + ((size_t)g*B_ROWS + b)*6;
  #pragma unroll
  for (int e=0;e<6;++e) dst[e] = p[e]*inv;
}

// ------- GEMM2 (gemm1-style): 64x128 block, A=Hb via LDS dbuf, B=W2F frags in regs -------
// 4 waves (1m x 4n), wave tile 64x32: eacc/oacc 2 x f32x16. 24 K-subtiles (6 experts
// x 4 tiles of BK=64). Counted vmcnt(4); gates+bias preloaded to LDS (no stray VMEM).

#define SGA2(S, BUF) do{ \
  const int e_  = (S) >> 2; \
  const int eid_= (e_ < 4) ? e_ : (g*2 + e_); \
  const u16* ga_ = Hb + (size_t)(row0 + (tid>>3))*NW1P + eid_*256 + ((S)&3)*64 + sSl2*8; \
  gload_lds16(ga_,                     &LA[BUF][tid*8]); \
  gload_lds16(ga_ + (size_t)32*NW1P,   &LA[BUF][2048 + tid*8]); \
}while(0)

#define LOADB2(S, BV) do{ \
  const int e_  = (S) >> 2; \
  const int eid_= (e_ < 4) ? e_ : (g*2 + e_); \
  const size_t base_ = ((size_t)(eid_*4 + wn)*16 + ((S)&3)*4)*512; \
  _Pragma("unroll") for (int kk=0;kk<4;++kk) \
    BV[kk] = *(const s16x8*)(pB2 + base_ + kk*512); \
}while(0)

#define COMPUTE2(BUF, BV) do{ \
  _Pragma("unroll") for (int kk=0;kk<4;++kk){ \
    s16x8 av[2]; \
    _Pragma("unroll") for (int mf=0;mf<2;++mf){ \
      const int row_ = mf*32 + l31; \
      av[mf] = *(const s16x8*)&LA[BUF][(row_<<6) + (((((kk<<1)|l5)) ^ (row_&7))<<3)]; \
    } \
    __builtin_amdgcn_s_setprio(1); \
    eacc[0] = __builtin_amdgcn_mfma_f32_32x32x16_bf16(av[0], BV[kk], eacc[0], 0, 0, 0); \
    eacc[1] = __builtin_amdgcn_mfma_f32_32x32x16_bf16(av[1], BV[kk], eacc[1], 0, 0, 0); \
    __builtin_amdgcn_s_setprio(0); \
  } \
}while(0)

#define EPI2(E) do{ \
  const float bias_ = bsm[(E)*128 + wn*32 + l31]; \
  _Pragma("unroll") for (int mf=0;mf<2;++mf){ \
    _Pragma("unroll") for (int r=0;r<16;++r){ \
      const int rl_ = mf*32 + 4*l5 + (r&3) + 8*(r>>2); \
      float v = eacc[mf][r] + bias_; \
      v = v > 0.f ? v : 0.f; \
      oacc[mf][r] += gsm[rl_*6 + (E)] * v; \
      eacc[mf][r] = 0.f; \
    } \
  } \
}while(0)

__global__ __launch_bounds__(256, 2) void gemm2_kernel(
    const u16* __restrict__ Hb, const u16* __restrict__ W2F,
    const float* __restrict__ b2c, const float* __restrict__ gts,
    float* __restrict__ outp)
{
  __shared__ __attribute__((aligned(16))) u16 LA[2][4096];  // 2 x 8 KB (64 rows x 64 k)
  __shared__ float gsm[64*6];
  __shared__ float bsm[6*128];
  const int tid  = threadIdx.x;
  const int lane = tid & 63;
  const int wn   = tid >> 6;          // 0..3
  const int l31  = lane & 31, l5 = lane >> 5;

  const int bid = blockIdx.x;         // 768 = 256 mt * 3 g
  const int mt  = bid / 3;
  const int g   = bid - mt*3;
  const int row0 = mt*64;

  const int sSl2 = (tid & 7) ^ ((tid >> 3) & 7);
  const u16* pB2 = W2F + lane*8;

  // preload gates (64 rows x 6) and biases (6 experts x 128 cols) into LDS
  for (int i = tid; i < 384; i += 256)
    gsm[i] = gts[((size_t)g*B_ROWS + row0)*6 + i];
  for (int i = tid; i < 768; i += 256){
    const int e_ = i >> 7;
    const int eid_ = (e_ < 4) ? e_ : (g*2 + e_);
    bsm[i] = b2c[eid_*128 + (i & 127)];
  }

  f32x16 eacc[2], oacc[2];
  #pragma unroll
  for (int mf=0;mf<2;++mf)
    #pragma unroll
    for (int r=0;r<16;++r){ eacc[mf][r] = 0.f; oacc[mf][r] = 0.f; }

  s16x8 bvA[4], bvB[4];

  SGA2(0, 0);
  LOADB2(0, bvA);
  VM0; BAR;

  #pragma unroll 1
  for (int i=0; i<12; ++i){
    const int s = 2*i;
    SGA2(s+1, 1);                 // 2 gld_lds
    LOADB2(s+1, bvB);             // 4 b128
    COMPUTE2(0, bvA);
    W4; BAR;                      // waits the 2 gld_lds only
    if (i < 11){ SGA2(s+2, 0); LOADB2(s+2, bvA); }
    COMPUTE2(1, bvB);
    if (((s+1) & 3) == 3) EPI2((s+1) >> 2);
    W4; BAR;
  }

  // store: out[g][row0+rl][wn*32+l31]
  #pragma unroll
  for (int mf=0;mf<2;++mf){
    #pragma unroll
    for (int r=0;r<16;++r){
      const int rl = mf*32 + 4*l5 + (r&3) + 8*(r>>2);
      outp[((size_t)g*B_ROWS + row0 + rl)*H2N + wn*32 + l31] = oacc[mf][r];
    }
  }
}

extern "C" void kernel_launch(void* const* d_in, const int* in_sizes, int n_in,
                              void* d_out, int out_size, void* d_ws, size_t ws_size,
                              hipStream_t stream)
{
  (void)in_sizes; (void)n_in; (void)out_size; (void)ws_size;
  const float* x   = (const float*)d_in[0];
  const float* sW1 = (const float*)d_in[2];
  const float* sb1 = (const float*)d_in[3];
  const float* sW2 = (const float*)d_in[4];
  const float* sb2 = (const float*)d_in[5];
  const float* dW1 = (const float*)d_in[6];
  const float* db1 = (const float*)d_in[7];
  const float* dW2 = (const float*)d_in[8];
  const float* db2 = (const float*)d_in[9];
  const float* gW1 = (const float*)d_in[10];
  const float* gb1 = (const float*)d_in[11];
  const float* gW2 = (const float*)d_in[12];
  const float* gb2 = (const float*)d_in[13];
  float* outp = (float*)d_out;

  char* ws = (char*)d_ws;
  u16*   Xb  = (u16*  )(ws + 0);          // 16384*1024*2      = 33554432
  u16*   W1F = (u16*  )(ws + 33554432);   // 88*64*64*8*2      =  5767168
  float* b1c = (float*)(ws + 39321600);   // 2816*4            =    11264
  u16*   W2F = (u16*  )(ws + 39332864);   // 10*4*16*64*8*2    =   655360
  float* b2c = (float*)(ws + 39988224);   // 10*128*4          =     5120
  float* gts = (float*)(ws + 39993344);   // 3*16384*6*4       =  1179648
  u16*   Hb  = (u16*  )(ws + 41172992);   // 16384*2816*2      = 92274688  (end ~133.4 MB)

  pack_w1_kernel<<<dim3(704),  dim3(256), 0, stream>>>(sW1,dW1,gW1,sb1,db1,gb1,W1F,b1c);
  pack_w2_kernel<<<dim3(160),  dim3(256), 0, stream>>>(sW2,dW2,sb2,db2,W2F,b2c);
  cast_x_kernel <<<dim3(8192), dim3(256), 0, stream>>>(x, Xb);
  gemm1_kernel  <<<dim3(704),  dim3(512), 0, stream>>>(Xb, W1F, b1c, Hb);
  gates_kernel  <<<dim3(192),  dim3(256), 0, stream>>>(Hb, gW2, gb2, gts);
  gemm2_kernel  <<<dim3(768),  dim3(256), 0, stream>>>(Hb, W2F, b2c, gts, outp);
}